// Round 2
// baseline (340.897 us; speedup 1.0000x reference)
//
#include <hip/hip_runtime.h>
#include <stdint.h>

// B=4, N=1024, C=128, P=16 positions, HEADS=16, DH=128, D=2048, MASK_NUM=25, SCALE=0.125
typedef __attribute__((ext_vector_type(8))) short s8v;   // 8 bf16 (A/B frag)
typedef __attribute__((ext_vector_type(4))) short s4v;
typedef __attribute__((ext_vector_type(4))) float f4v;   // C/D frag

#define MFMA(a,b,c) __builtin_amdgcn_mfma_f32_16x16x32_bf16((a),(b),(c),0,0,0)

__device__ __forceinline__ short f2bf(float f){   // RNE float->bf16 bits
  union { float f; unsigned u; } a; a.f = f;
  unsigned r = (a.u + 0x7fffu + ((a.u >> 16) & 1u)) >> 16;
  return (short)r;
}

// ---------- combined mask weights: wcomb[c] = sum_o Wl[o]*Wq[o,c]; wcomb[128] = sum_o Wl[o]*bq[o] + bl ----------
__global__ void k_wcomb(const float* __restrict__ Wq, const float* __restrict__ bq,
                        const float* __restrict__ Wl, const float* __restrict__ bl,
                        float* __restrict__ wcomb){
  int c = threadIdx.x;            // 128 threads
  float s = 0.f;
  for (int o = 0; o < 128; ++o) s += Wl[o] * Wq[o*128 + c];
  wcomb[c] = s;
  if (c == 0){
    float t = 0.f; for (int o = 0; o < 128; ++o) t += Wl[o] * bq[o];
    wcomb[128] = t + bl[0];
  }
}

// ---------- weights fp32 -> bf16 ----------
__global__ void k_conv_w(const float* __restrict__ Wq, const float* __restrict__ Wk,
                         const float* __restrict__ Wv, const float* __restrict__ Wo,
                         short* __restrict__ wq16, short* __restrict__ wk16,
                         short* __restrict__ wv16, short* __restrict__ wo16){
  int i = blockIdx.x*256 + threadIdx.x;      // grid 16384 -> exactly 4194304
  wo16[i] = f2bf(Wo[i]);
  if (i < 16384){ wq16[i] = f2bf(Wq[i]); wk16[i] = f2bf(Wk[i]); wv16[i] = f2bf(Wv[i]); }
}

// ---------- x fp32 -> bf16, plus fused logits (fp32): logit[t] = (1/16)*sum x[t,:]*wcomb[flat%128] + const ----------
__global__ __launch_bounds__(256) void k_conv_x(const float* __restrict__ x, const float* __restrict__ wcomb,
                                                short* __restrict__ x16, float* __restrict__ logits){
  __shared__ float wc[128];
  __shared__ float part[4];
  int t = blockIdx.x, tid = threadIdx.x;     // one block per token
  if (tid < 128) wc[tid] = wcomb[tid];
  __syncthreads();
  const float* xp = x + (size_t)t*2048;
  short* op = x16 + (size_t)t*2048;
  float s = 0.f;
  #pragma unroll
  for (int j = 0; j < 2; ++j){
    int idx = j*1024 + tid*4;
    float4 v = *(const float4*)(xp + idx);
    s4v o; o.x = f2bf(v.x); o.y = f2bf(v.y); o.z = f2bf(v.z); o.w = f2bf(v.w);
    *(s4v*)(op + idx) = o;
    s += v.x*wc[idx&127] + v.y*wc[(idx+1)&127] + v.z*wc[(idx+2)&127] + v.w*wc[(idx+3)&127];
  }
  for (int off = 32; off; off >>= 1) s += __shfl_down(s, off);
  if ((tid&63) == 0) part[tid>>6] = s;
  __syncthreads();
  if (tid == 0) logits[t] = (part[0]+part[1]+part[2]+part[3])*(1.f/16.f) + wcomb[128];
}

// ---------- per-batch softmax over 1024 tokens + 25th-smallest threshold + snap-to-1 mask ----------
__global__ __launch_bounds__(1024) void k_mask(const float* __restrict__ logits, float* __restrict__ maskout){
  int b = blockIdx.x, tid = threadIdx.x;     // 1024 threads
  __shared__ float vals[1024];
  __shared__ float redf[16];
  __shared__ unsigned long long redk[16];
  __shared__ float sb;
  __shared__ unsigned long long sk;
  int w = tid>>6, lane = tid&63;
  float lg = logits[b*1024 + tid];
  float v = lg;
  for (int off = 32; off; off >>= 1) v = fmaxf(v, __shfl_down(v, off));
  if (lane == 0) redf[w] = v;
  __syncthreads();
  if (tid == 0){ float m = redf[0]; for (int i = 1; i < 16; ++i) m = fmaxf(m, redf[i]); sb = m; }
  __syncthreads();
  float gmax = sb;
  float e = __expf(lg - gmax);
  __syncthreads();
  v = e;
  for (int off = 32; off; off >>= 1) v += __shfl_down(v, off);
  if (lane == 0) redf[w] = v;
  __syncthreads();
  if (tid == 0){ float s2 = 0.f; for (int i = 0; i < 16; ++i) s2 += redf[i]; sb = s2; }
  __syncthreads();
  float prob = e / sb;
  vals[tid] = prob;
  __syncthreads();
  float thr = 0.f;
  // extract 25 minima (value,index) -> thr = 25th smallest (multiplicity-correct, matches top_k)
  for (int k = 0; k < 25; ++k){
    float pv = vals[tid];
    unsigned hi = __float_as_uint(pv), lo2 = (unsigned)tid;   // positive floats: bits are order-monotone
    for (int off = 32; off; off >>= 1){
      unsigned ohi = __shfl_down(hi, off), olo = __shfl_down(lo2, off);
      if (ohi < hi || (ohi == hi && olo < lo2)){ hi = ohi; lo2 = olo; }
    }
    if (lane == 0) redk[w] = (((unsigned long long)hi)<<32) | lo2;
    __syncthreads();
    if (tid == 0){ unsigned long long mk = redk[0]; for (int i = 1; i < 16; ++i) if (redk[i] < mk) mk = redk[i]; sk = mk; }
    __syncthreads();
    unsigned long long mk = sk;
    if (k == 24) thr = __uint_as_float((unsigned)(mk>>32));
    if ((unsigned)tid == (unsigned)(mk & 0xffffffffull)) vals[tid] = 2.0f;  // exclude this instance
    __syncthreads();
  }
  maskout[b*1024 + tid] = prob > thr ? 1.0f : prob;
}

// ---------- QKV projection: out(M=65536,128) = x16(M,128) . W^T(128,128) + bias, optional *0.125 for Q ----------
__global__ __launch_bounds__(256) void k_qkv(const short* __restrict__ x16, const short* __restrict__ w16,
                                             const float* __restrict__ bias, short* __restrict__ out16, int doscale){
  __shared__ short At[64*136];    // 64 rows x 128, stride 136 (16B aligned, conflict-free frag reads)
  __shared__ short Wt[128*136];
  int tid = threadIdx.x, lane = tid&63, w = tid>>6;
  int m0 = blockIdx.x*64;
  #pragma unroll
  for (int i = 0; i < 4; ++i){
    int ch = tid + 256*i; int r = ch>>4, c8 = (ch&15)*8;
    *(s8v*)&At[r*136 + c8] = *(const s8v*)(x16 + (size_t)(m0+r)*128 + c8);
  }
  #pragma unroll
  for (int i = 0; i < 8; ++i){
    int ch = tid + 256*i; int r = ch>>4, c8 = (ch&15)*8;
    *(s8v*)&Wt[r*136 + c8] = *(const s8v*)(w16 + r*128 + c8);
  }
  __syncthreads();
  int ln = lane&15, q = lane>>4;
  f4v acc[8];
  #pragma unroll
  for (int cb = 0; cb < 8; ++cb) acc[cb] = f4v{0.f,0.f,0.f,0.f};
  #pragma unroll
  for (int ks = 0; ks < 4; ++ks){
    s8v a = *(const s8v*)&At[(w*16+ln)*136 + ks*32 + q*8];
    #pragma unroll
    for (int cb = 0; cb < 8; ++cb){
      s8v bb = *(const s8v*)&Wt[(cb*16+ln)*136 + ks*32 + q*8];
      acc[cb] = MFMA(a, bb, acc[cb]);
    }
  }
  float sc = doscale ? 0.125f : 1.0f;
  #pragma unroll
  for (int cb = 0; cb < 8; ++cb){
    int col = cb*16 + ln;
    float bv = bias[col];
    #pragma unroll
    for (int r = 0; r < 4; ++r){
      int row = m0 + w*16 + q*4 + r;
      out16[(size_t)row*128 + col] = f2bf((acc[cb][r] + bv)*sc);
    }
  }
}

// ---------- V transpose per (b,h): (n,c) -> Vt[bh][c][n] ----------
__global__ __launch_bounds__(256) void k_vtrans(const short* __restrict__ v16, short* __restrict__ vt16){
  __shared__ short T[128*136];
  int bh = blockIdx.x, nt = blockIdx.y;
  int b = bh>>4, h = bh&15, n0 = nt*128;
  int tid = threadIdx.x;
  #pragma unroll
  for (int i = 0; i < 8; ++i){
    int ch = tid + 256*i; int r = ch>>4, c8 = (ch&15)*8;
    *(s8v*)&T[r*136 + c8] = *(const s8v*)(v16 + (size_t)(b*1024 + n0 + r)*2048 + h*128 + c8);
  }
  __syncthreads();
  #pragma unroll
  for (int i = 0; i < 8; ++i){
    int ch = tid + 256*i; int c = ch>>4, r8 = (ch&15)*8;
    s8v o;
    #pragma unroll
    for (int j = 0; j < 8; ++j) o[j] = T[(r8+j)*136 + c];
    *(s8v*)(vt16 + (size_t)(bh*128 + c)*1024 + n0 + r8) = o;
  }
}

// ---------- flash attention per (b,h): Q pre-scaled, S *= mask[j] pre-softmax, P *= mask[j] pre-PV ----------
__global__ __launch_bounds__(256) void k_attn(const short* __restrict__ q16, const short* __restrict__ k16,
                                              const short* __restrict__ vt16, const float* __restrict__ maskp,
                                              short* __restrict__ a16){
  __shared__ short Qs[64*136];
  __shared__ short Ks[64*136];
  __shared__ short Vs[128*72];   // rows=c, cols=j-local (64)+pad8
  __shared__ short Ps[64*72];
  int it = blockIdx.x, h = blockIdx.y, b = blockIdx.z;
  int i0 = it*64;
  int tid = threadIdx.x, lane = tid&63, w = tid>>6;
  int ln = lane&15, q = lane>>4;
  #pragma unroll
  for (int i = 0; i < 4; ++i){
    int ch = tid + 256*i; int r = ch>>4, c8 = (ch&15)*8;
    *(s8v*)&Qs[r*136 + c8] = *(const s8v*)(q16 + (size_t)(b*1024 + i0 + r)*2048 + h*128 + c8);
  }
  f4v O[8];
  #pragma unroll
  for (int cb = 0; cb < 8; ++cb) O[cb] = f4v{0.f,0.f,0.f,0.f};
  float mo[4], lo[4];
  #pragma unroll
  for (int r = 0; r < 4; ++r){ mo[r] = -3.0e38f; lo[r] = 0.f; }
  for (int jt = 0; jt < 16; ++jt){
    int j0 = jt*64;
    __syncthreads();   // previous PV reads done before restage
    #pragma unroll
    for (int i = 0; i < 4; ++i){
      int ch = tid + 256*i; int r = ch>>4, c8 = (ch&15)*8;
      *(s8v*)&Ks[r*136 + c8] = *(const s8v*)(k16 + (size_t)(b*1024 + j0 + r)*2048 + h*128 + c8);
    }
    #pragma unroll
    for (int i = 0; i < 4; ++i){
      int ch = tid + 256*i; int c = ch>>3, j8 = (ch&7)*8;
      *(s8v*)&Vs[c*72 + j8] = *(const s8v*)(vt16 + (size_t)((b*16+h)*128 + c)*1024 + j0 + j8);
    }
    __syncthreads();
    f4v sa[4];
    #pragma unroll
    for (int cb = 0; cb < 4; ++cb) sa[cb] = f4v{0.f,0.f,0.f,0.f};
    #pragma unroll
    for (int ks = 0; ks < 4; ++ks){   // FIX: K-dim = DH = 128 -> 4 x 32 (was 2 -> only half the head dim)
      s8v a = *(const s8v*)&Qs[(w*16+ln)*136 + ks*32 + q*8];
      #pragma unroll
      for (int cb = 0; cb < 4; ++cb){
        s8v bb = *(const s8v*)&Ks[(cb*16+ln)*136 + ks*32 + q*8];
        sa[cb] = MFMA(a, bb, sa[cb]);
      }
    }
    float mv[4];
    #pragma unroll
    for (int cb = 0; cb < 4; ++cb) mv[cb] = maskp[b*1024 + j0 + cb*16 + ln];
    float sv[4][4];
    #pragma unroll
    for (int cb = 0; cb < 4; ++cb)
      #pragma unroll
      for (int r = 0; r < 4; ++r) sv[cb][r] = sa[cb][r]*mv[cb];
    float mx[4];
    #pragma unroll
    for (int r = 0; r < 4; ++r) mx[r] = fmaxf(fmaxf(sv[0][r], sv[1][r]), fmaxf(sv[2][r], sv[3][r]));
    #pragma unroll
    for (int off = 1; off < 16; off <<= 1)
      #pragma unroll
      for (int r = 0; r < 4; ++r) mx[r] = fmaxf(mx[r], __shfl_xor(mx[r], off));
    float mnew[4], al[4], rs[4];
    #pragma unroll
    for (int r = 0; r < 4; ++r){
      mnew[r] = fmaxf(mo[r], mx[r]);
      al[r] = __expf(mo[r] - mnew[r]);
      rs[r] = 0.f;
    }
    #pragma unroll
    for (int cb = 0; cb < 4; ++cb){
      #pragma unroll
      for (int r = 0; r < 4; ++r){
        float pp = __expf(sv[cb][r] - mnew[r]);
        rs[r] += pp;
        Ps[(w*16 + q*4 + r)*72 + cb*16 + ln] = f2bf(pp*mv[cb]);
      }
    }
    #pragma unroll
    for (int off = 1; off < 16; off <<= 1)
      #pragma unroll
      for (int r = 0; r < 4; ++r) rs[r] += __shfl_xor(rs[r], off);
    #pragma unroll
    for (int r = 0; r < 4; ++r){ lo[r] = lo[r]*al[r] + rs[r]; mo[r] = mnew[r]; }
    #pragma unroll
    for (int cb = 0; cb < 8; ++cb)
      #pragma unroll
      for (int r = 0; r < 4; ++r) O[cb][r] *= al[r];
    __syncthreads();   // Ps visible
    #pragma unroll
    for (int ks = 0; ks < 2; ++ks){
      s8v a = *(const s8v*)&Ps[(w*16+ln)*72 + ks*32 + q*8];
      #pragma unroll
      for (int cb = 0; cb < 8; ++cb){
        s8v bb = *(const s8v*)&Vs[(cb*16+ln)*72 + ks*32 + q*8];
        O[cb] = MFMA(a, bb, O[cb]);
      }
    }
  }
  #pragma unroll
  for (int cb = 0; cb < 8; ++cb){
    int col = cb*16 + ln;
    #pragma unroll
    for (int r = 0; r < 4; ++r){
      int row = i0 + w*16 + q*4 + r;
      a16[(size_t)(b*1024 + row)*2048 + h*128 + col] = f2bf(O[cb][r] / lo[r]);
    }
  }
}

// ---------- output projection: out(4096,2048) = A16 . Wo^T + bo (fp32 out), XOR-swizzled LDS ----------
__global__ __launch_bounds__(256) void k_out(const short* __restrict__ a16, const short* __restrict__ wo16,
                                             const float* __restrict__ bo, float* __restrict__ out){
  __shared__ short As[128*64];
  __shared__ short Bs[128*64];
  int tid = threadIdx.x, lane = tid&63, w = tid>>6;
  int m0 = blockIdx.x*128, n0 = blockIdx.y*128;
  int wrow = (w>>1)*64, wcol = (w&1)*64;
  int ln = lane&15, q = lane>>4;
  f4v acc[4][4];
  #pragma unroll
  for (int i = 0; i < 4; ++i)
    #pragma unroll
    for (int j = 0; j < 4; ++j) acc[i][j] = f4v{0.f,0.f,0.f,0.f};
  for (int it = 0; it < 32; ++it){
    int k0 = it*64;
    __syncthreads();
    #pragma unroll
    for (int i = 0; i < 4; ++i){
      int ch = tid + 256*i;          // 0..1023
      int r = ch>>3, c = ch&7;
      int gc8 = (c ^ (r&7))*8;       // LDS chunk c holds global chunk c^(r&7)
      *(s8v*)&As[r*64 + c*8] = *(const s8v*)(a16  + (size_t)(m0+r)*2048 + k0 + gc8);
      *(s8v*)&Bs[r*64 + c*8] = *(const s8v*)(wo16 + (size_t)(n0+r)*2048 + k0 + gc8);
    }
    __syncthreads();
    #pragma unroll
    for (int ks = 0; ks < 2; ++ks){
      s8v a[4], bb[4];
      int swz = ((ks*4 + q) ^ (ln&7))*8;
      #pragma unroll
      for (int i = 0; i < 4; ++i){
        a[i]  = *(const s8v*)&As[(wrow + i*16 + ln)*64 + swz];
        bb[i] = *(const s8v*)&Bs[(wcol + i*16 + ln)*64 + swz];
      }
      #pragma unroll
      for (int i = 0; i < 4; ++i)
        #pragma unroll
        for (int j = 0; j < 4; ++j) acc[i][j] = MFMA(a[i], bb[j], acc[i][j]);
    }
  }
  #pragma unroll
  for (int j = 0; j < 4; ++j){
    int col = n0 + wcol + j*16 + ln;
    float bv = bo[col];
    #pragma unroll
    for (int i = 0; i < 4; ++i)
      #pragma unroll
      for (int r = 0; r < 4; ++r){
        int row = m0 + wrow + i*16 + q*4 + r;
        out[(size_t)row*2048 + col] = acc[i][j][r] + bv;
      }
  }
}

extern "C" void kernel_launch(void* const* d_in, const int* in_sizes, int n_in,
                              void* d_out, int out_size, void* d_ws, size_t ws_size,
                              hipStream_t stream){
  const float* x  = (const float*)d_in[0];
  const float* Wq = (const float*)d_in[1];
  const float* bq = (const float*)d_in[2];
  const float* Wk = (const float*)d_in[3];
  const float* bk = (const float*)d_in[4];
  const float* Wv = (const float*)d_in[5];
  const float* bv = (const float*)d_in[6];
  const float* Wl = (const float*)d_in[7];
  const float* bl = (const float*)d_in[8];
  const float* Wo = (const float*)d_in[9];
  const float* bo = (const float*)d_in[10];
  float* out = (float*)d_out;

  char* p = (char*)d_ws;
  size_t off = 0;
  auto take = [&](size_t bytes)->char*{ char* r = p + off; off = (off + bytes + 255) & ~(size_t)255; return r; };
  short* x16   = (short*)take(16777216);  // (b,n,p,c) bf16; reused as attn-out after QKV consumed it
  short* q16   = (short*)take(16777216);
  short* k16   = (short*)take(16777216);
  short* v16   = (short*)take(16777216);
  short* vt16  = (short*)take(16777216);  // [b*16+h][c][n]
  short* wo16  = (short*)take(8388608);
  short* wq16  = (short*)take(32768);
  short* wk16  = (short*)take(32768);
  short* wv16  = (short*)take(32768);
  float* wcomb = (float*)take(4*129);
  float* logits= (float*)take(4*4096);
  float* maskp = (float*)take(4*4096);
  short* a16 = x16;   // alias: x16 dead after the three k_qkv launches

  k_wcomb <<<1, 128, 0, stream>>>(Wq, bq, Wl, bl, wcomb);
  k_conv_w<<<16384, 256, 0, stream>>>(Wq, Wk, Wv, Wo, wq16, wk16, wv16, wo16);
  k_conv_x<<<4096, 256, 0, stream>>>(x, wcomb, x16, logits);
  k_mask  <<<4, 1024, 0, stream>>>(logits, maskp);
  k_qkv   <<<1024, 256, 0, stream>>>(x16, wq16, bq, q16, 1);   // Q pre-scaled by 0.125
  k_qkv   <<<1024, 256, 0, stream>>>(x16, wk16, bk, k16, 0);
  k_qkv   <<<1024, 256, 0, stream>>>(x16, wv16, bv, v16, 0);
  k_vtrans<<<dim3(64, 8), 256, 0, stream>>>(v16, vt16);
  k_attn  <<<dim3(16, 16, 4), 256, 0, stream>>>(q16, k16, vt16, maskp, a16);
  k_out   <<<dim3(32, 16), 256, 0, stream>>>(a16, wo16, bo, out);
}

// Round 3
// 298.838 us; speedup vs baseline: 1.1407x; 1.1407x over previous
//
#include <hip/hip_runtime.h>
#include <stdint.h>

// B=4, N=1024, C=128, P=16 positions, HEADS=16, DH=128, D=2048, MASK_NUM=25, SCALE=0.125
typedef __attribute__((ext_vector_type(8))) short s8v;   // 8 bf16 (A/B frag)
typedef __attribute__((ext_vector_type(4))) short s4v;
typedef __attribute__((ext_vector_type(4))) float f4v;   // C/D frag

#define MFMA(a,b,c) __builtin_amdgcn_mfma_f32_16x16x32_bf16((a),(b),(c),0,0,0)

__device__ __forceinline__ short f2bf(float f){   // RNE float->bf16 bits
  union { float f; unsigned u; } a; a.f = f;
  unsigned r = (a.u + 0x7fffu + ((a.u >> 16) & 1u)) >> 16;
  return (short)r;
}

// async global->LDS DMA, 16B per lane; LDS dest = wave-uniform base + lane*16
__device__ __forceinline__ void gld16(const void* g, void* l){
  __builtin_amdgcn_global_load_lds((const __attribute__((address_space(1))) void*)g,
                                   (__attribute__((address_space(3))) void*)l, 16, 0, 0);
}

// ---------- combined mask weights: wcomb[c] = sum_o Wl[o]*Wq[o,c]; wcomb[128] = sum_o Wl[o]*bq[o] + bl ----------
__global__ void k_wcomb(const float* __restrict__ Wq, const float* __restrict__ bq,
                        const float* __restrict__ Wl, const float* __restrict__ bl,
                        float* __restrict__ wcomb){
  int c = threadIdx.x;            // 128 threads
  float s = 0.f;
  for (int o = 0; o < 128; ++o) s += Wl[o] * Wq[o*128 + c];
  wcomb[c] = s;
  if (c == 0){
    float t = 0.f; for (int o = 0; o < 128; ++o) t += Wl[o] * bq[o];
    wcomb[128] = t + bl[0];
  }
}

// ---------- weights fp32 -> bf16 ----------
__global__ void k_conv_w(const float* __restrict__ Wq, const float* __restrict__ Wk,
                         const float* __restrict__ Wv, const float* __restrict__ Wo,
                         short* __restrict__ wq16, short* __restrict__ wk16,
                         short* __restrict__ wv16, short* __restrict__ wo16){
  int i = blockIdx.x*256 + threadIdx.x;      // grid 16384 -> exactly 4194304
  wo16[i] = f2bf(Wo[i]);
  if (i < 16384){ wq16[i] = f2bf(Wq[i]); wk16[i] = f2bf(Wk[i]); wv16[i] = f2bf(Wv[i]); }
}

// ---------- x fp32 -> bf16, plus fused logits (fp32) ----------
__global__ __launch_bounds__(256) void k_conv_x(const float* __restrict__ x, const float* __restrict__ wcomb,
                                                short* __restrict__ x16, float* __restrict__ logits){
  __shared__ float wc[128];
  __shared__ float part[4];
  int t = blockIdx.x, tid = threadIdx.x;     // one block per token
  if (tid < 128) wc[tid] = wcomb[tid];
  __syncthreads();
  const float* xp = x + (size_t)t*2048;
  short* op = x16 + (size_t)t*2048;
  float s = 0.f;
  #pragma unroll
  for (int j = 0; j < 2; ++j){
    int idx = j*1024 + tid*4;
    float4 v = *(const float4*)(xp + idx);
    s4v o; o.x = f2bf(v.x); o.y = f2bf(v.y); o.z = f2bf(v.z); o.w = f2bf(v.w);
    *(s4v*)(op + idx) = o;
    s += v.x*wc[idx&127] + v.y*wc[(idx+1)&127] + v.z*wc[(idx+2)&127] + v.w*wc[(idx+3)&127];
  }
  for (int off = 32; off; off >>= 1) s += __shfl_down(s, off);
  if ((tid&63) == 0) part[tid>>6] = s;
  __syncthreads();
  if (tid == 0) logits[t] = (part[0]+part[1]+part[2]+part[3])*(1.f/16.f) + wcomb[128];
}

// ---------- softmax + 25th-smallest threshold mask: one wave per batch, no barriers ----------
__global__ __launch_bounds__(64) void k_mask(const float* __restrict__ logits, float* __restrict__ maskout){
  int b = blockIdx.x, lane = threadIdx.x;
  float v[16];
  #pragma unroll
  for (int i = 0; i < 16; ++i) v[i] = logits[b*1024 + i*64 + lane];
  float mx = v[0];
  #pragma unroll
  for (int i = 1; i < 16; ++i) mx = fmaxf(mx, v[i]);
  #pragma unroll
  for (int off = 32; off; off >>= 1) mx = fmaxf(mx, __shfl_xor(mx, off));
  float s = 0.f;
  #pragma unroll
  for (int i = 0; i < 16; ++i){ v[i] = __expf(v[i] - mx); s += v[i]; }
  #pragma unroll
  for (int off = 32; off; off >>= 1) s += __shfl_xor(s, off);
  float p[16];
  #pragma unroll
  for (int i = 0; i < 16; ++i){ p[i] = v[i] / s; v[i] = p[i]; }
  float thr = 0.f;
  for (int k = 0; k < 25; ++k){
    float lm = v[0]; int li = 0;
    #pragma unroll
    for (int i = 1; i < 16; ++i){ if (v[i] < lm){ lm = v[i]; li = i; } }
    float gm = lm;
    #pragma unroll
    for (int off = 32; off; off >>= 1) gm = fminf(gm, __shfl_xor(gm, off));
    if (k == 24) thr = gm;
    unsigned long long ball = __ballot(lm == gm);
    int owner = __ffsll((unsigned long long)ball) - 1;
    bool rm = (lane == owner);
    #pragma unroll
    for (int i = 0; i < 16; ++i){ if (rm && i == li) v[i] = 2.0f; }  // remove one instance
  }
  #pragma unroll
  for (int i = 0; i < 16; ++i)
    maskout[b*1024 + i*64 + lane] = p[i] > thr ? 1.0f : p[i];
}

// ---------- merged QKV projection: stage A once, 3 sequential weight passes ----------
__global__ __launch_bounds__(256) void k_qkv3(const short* __restrict__ x16,
                                              const short* __restrict__ wq16, const short* __restrict__ wk16,
                                              const short* __restrict__ wv16,
                                              const float* __restrict__ bq, const float* __restrict__ bk,
                                              const float* __restrict__ bv,
                                              short* __restrict__ q16, short* __restrict__ k16,
                                              short* __restrict__ v16o){
  __shared__ short At[64*136];
  __shared__ short Wt[128*136];
  int tid = threadIdx.x, lane = tid&63, w = tid>>6;
  int m0 = blockIdx.x*64;
  #pragma unroll
  for (int i = 0; i < 4; ++i){
    int ch = tid + 256*i; int r = ch>>4, c8 = (ch&15)*8;
    *(s8v*)&At[r*136 + c8] = *(const s8v*)(x16 + (size_t)(m0+r)*128 + c8);
  }
  int ln = lane&15, q = lane>>4;
  const short* ws[3] = {wq16, wk16, wv16};
  const float* bs[3] = {bq, bk, bv};
  short*       os[3] = {q16, k16, v16o};
  for (int ps = 0; ps < 3; ++ps){
    if (ps) __syncthreads();   // prior pass's reads of Wt done
    #pragma unroll
    for (int i = 0; i < 8; ++i){
      int ch = tid + 256*i; int r = ch>>4, c8 = (ch&15)*8;
      *(s8v*)&Wt[r*136 + c8] = *(const s8v*)(ws[ps] + r*128 + c8);
    }
    __syncthreads();
    f4v acc[8];
    #pragma unroll
    for (int cb = 0; cb < 8; ++cb) acc[cb] = f4v{0.f,0.f,0.f,0.f};
    #pragma unroll
    for (int ks = 0; ks < 4; ++ks){
      s8v a = *(const s8v*)&At[(w*16+ln)*136 + ks*32 + q*8];
      #pragma unroll
      for (int cb = 0; cb < 8; ++cb){
        s8v bb = *(const s8v*)&Wt[(cb*16+ln)*136 + ks*32 + q*8];
        acc[cb] = MFMA(a, bb, acc[cb]);
      }
    }
    float sc = (ps == 0) ? 0.125f : 1.0f;
    short* op = os[ps];
    const float* bp = bs[ps];
    #pragma unroll
    for (int cb = 0; cb < 8; ++cb){
      int col = cb*16 + ln;
      float bv2 = bp[col];
      #pragma unroll
      for (int r = 0; r < 4; ++r){
        int row = m0 + w*16 + q*4 + r;
        op[(size_t)row*128 + col] = f2bf((acc[cb][r] + bv2)*sc);
      }
    }
  }
}

// ---------- V transpose per (b,h): (n,c) -> Vt[bh][c][n] ----------
__global__ __launch_bounds__(256) void k_vtrans(const short* __restrict__ v16, short* __restrict__ vt16){
  __shared__ short T[128*136];
  int bh = blockIdx.x, nt = blockIdx.y;
  int b = bh>>4, h = bh&15, n0 = nt*128;
  int tid = threadIdx.x;
  #pragma unroll
  for (int i = 0; i < 8; ++i){
    int ch = tid + 256*i; int r = ch>>4, c8 = (ch&15)*8;
    *(s8v*)&T[r*136 + c8] = *(const s8v*)(v16 + (size_t)(b*1024 + n0 + r)*2048 + h*128 + c8);
  }
  __syncthreads();
  #pragma unroll
  for (int i = 0; i < 8; ++i){
    int ch = tid + 256*i; int c = ch>>4, r8 = (ch&15)*8;
    s8v o;
    #pragma unroll
    for (int j = 0; j < 8; ++j) o[j] = T[(r8+j)*136 + c];
    *(s8v*)(vt16 + (size_t)(bh*128 + c)*1024 + n0 + r8) = o;
  }
}

// ---------- flash attention per (b,h): 128 Q-rows/block, Q in regs, K/V via global_load_lds + XOR swizzle ----------
__global__ __launch_bounds__(256, 2) void k_attn(const short* __restrict__ q16, const short* __restrict__ k16,
                                                 const short* __restrict__ vt16, const float* __restrict__ maskp,
                                                 short* __restrict__ a16){
  __shared__ short Ks[64*128];   // row j(64) x 16 chunks of 8; LDS chunk c holds global chunk c^(r&7)
  __shared__ short Vs[128*64];   // row c(128) x 8 chunks; same XOR
  __shared__ short Ps[128*72];   // P rows (wave-private 32 each) x 64 j + pad
  int it = blockIdx.x, h = blockIdx.y, b = blockIdx.z;
  int i0 = it*128;
  int tid = threadIdx.x, lane = tid&63, w = tid>>6;
  int ln = lane&15, q = lane>>4;
  // Q fragments (2 row-blocks x K=128) live in registers for the whole kernel
  s8v aq[2][4];
  const short* qbase = q16 + (size_t)(b*1024 + i0 + w*32)*2048 + h*128;
  #pragma unroll
  for (int rb = 0; rb < 2; ++rb)
    #pragma unroll
    for (int ks = 0; ks < 4; ++ks)
      aq[rb][ks] = *(const s8v*)(qbase + (size_t)(rb*16+ln)*2048 + ks*32 + q*8);
  f4v o[2][8];
  #pragma unroll
  for (int rb = 0; rb < 2; ++rb)
    #pragma unroll
    for (int cb = 0; cb < 8; ++cb) o[rb][cb] = f4v{0.f,0.f,0.f,0.f};
  float mo[2][4], lo[2][4];
  #pragma unroll
  for (int rb = 0; rb < 2; ++rb)
    #pragma unroll
    for (int r = 0; r < 4; ++r){ mo[rb][r] = -3.0e38f; lo[rb][r] = 0.f; }
  const short* kbase = k16 + (size_t)(b*1024)*2048 + h*128;
  const short* vbase = vt16 + (size_t)((b*16+h)*128)*1024;
  for (int jt = 0; jt < 16; ++jt){
    int j0 = jt*64;
    __syncthreads();   // all waves done reading Ks/Vs of previous tile before DMA overwrite
    #pragma unroll
    for (int t = 0; t < 4; ++t){   // K: 4 rows x 16 chunks per wave-load
      int r = w*16 + t*4 + (lane>>4);
      int c = lane&15;
      gld16(kbase + (size_t)(j0 + r)*2048 + ((c ^ (r&7))*8), &Ks[(w*16 + t*4)*128]);
    }
    #pragma unroll
    for (int t = 0; t < 4; ++t){   // V: 8 rows x 8 chunks per wave-load
      int r = w*32 + t*8 + (lane>>3);
      int c = lane&7;
      gld16(vbase + (size_t)r*1024 + j0 + ((c ^ (r&7))*8), &Vs[(w*32 + t*8)*64]);
    }
    __syncthreads();   // vmcnt(0) drain: DMA complete
    f4v sa[2][4];
    #pragma unroll
    for (int rb = 0; rb < 2; ++rb)
      #pragma unroll
      for (int cb = 0; cb < 4; ++cb) sa[rb][cb] = f4v{0.f,0.f,0.f,0.f};
    #pragma unroll
    for (int ks = 0; ks < 4; ++ks)
      #pragma unroll
      for (int cb = 0; cb < 4; ++cb){
        int r = cb*16 + ln;
        s8v bb = *(const s8v*)&Ks[r*128 + (((ks*4 + q) ^ (ln&7))*8)];
        sa[0][cb] = MFMA(aq[0][ks], bb, sa[0][cb]);
        sa[1][cb] = MFMA(aq[1][ks], bb, sa[1][cb]);
      }
    float mv[4];
    #pragma unroll
    for (int cb = 0; cb < 4; ++cb) mv[cb] = maskp[b*1024 + j0 + cb*16 + ln];
    #pragma unroll
    for (int rb = 0; rb < 2; ++rb){
      float sv[4][4];
      #pragma unroll
      for (int cb = 0; cb < 4; ++cb)
        #pragma unroll
        for (int r = 0; r < 4; ++r) sv[cb][r] = sa[rb][cb][r]*mv[cb];
      float mx[4];
      #pragma unroll
      for (int r = 0; r < 4; ++r) mx[r] = fmaxf(fmaxf(sv[0][r], sv[1][r]), fmaxf(sv[2][r], sv[3][r]));
      #pragma unroll
      for (int off = 1; off < 16; off <<= 1)
        #pragma unroll
        for (int r = 0; r < 4; ++r) mx[r] = fmaxf(mx[r], __shfl_xor(mx[r], off));
      float mnew[4], al[4], rs[4];
      #pragma unroll
      for (int r = 0; r < 4; ++r){
        mnew[r] = fmaxf(mo[rb][r], mx[r]);
        al[r] = __expf(mo[rb][r] - mnew[r]);
        rs[r] = 0.f;
      }
      #pragma unroll
      for (int cb = 0; cb < 4; ++cb)
        #pragma unroll
        for (int r = 0; r < 4; ++r){
          float pp = __expf(sv[cb][r] - mnew[r]);
          rs[r] += pp;
          Ps[(w*32 + rb*16 + q*4 + r)*72 + cb*16 + ln] = f2bf(pp*mv[cb]);
        }
      #pragma unroll
      for (int off = 1; off < 16; off <<= 1)
        #pragma unroll
        for (int r = 0; r < 4; ++r) rs[r] += __shfl_xor(rs[r], off);
      #pragma unroll
      for (int r = 0; r < 4; ++r){ lo[rb][r] = lo[rb][r]*al[r] + rs[r]; mo[rb][r] = mnew[r]; }
      #pragma unroll
      for (int cb = 0; cb < 8; ++cb)
        #pragma unroll
        for (int r = 0; r < 4; ++r) o[rb][cb][r] *= al[r];
    }
    __syncthreads();   // Ps writes drained before b128 reads
    #pragma unroll
    for (int ks = 0; ks < 2; ++ks){
      s8v pa[2];
      #pragma unroll
      for (int rb = 0; rb < 2; ++rb) pa[rb] = *(const s8v*)&Ps[(w*32 + rb*16 + ln)*72 + ks*32 + q*8];
      #pragma unroll
      for (int cb = 0; cb < 8; ++cb){
        int r = cb*16 + ln;
        s8v bb = *(const s8v*)&Vs[r*64 + (((ks*4 + q) ^ (ln&7))*8)];
        o[0][cb] = MFMA(pa[0], bb, o[0][cb]);
        o[1][cb] = MFMA(pa[1], bb, o[1][cb]);
      }
    }
  }
  #pragma unroll
  for (int rb = 0; rb < 2; ++rb)
    #pragma unroll
    for (int cb = 0; cb < 8; ++cb){
      int col = cb*16 + ln;
      #pragma unroll
      for (int r = 0; r < 4; ++r){
        int row = i0 + w*32 + rb*16 + q*4 + r;
        a16[(size_t)(b*1024 + row)*2048 + h*128 + col] = f2bf(o[rb][cb][r] / lo[rb][r]);
      }
    }
}

// ---------- output projection: out(4096,2048) = A16 . Wo^T + bo, global_load_lds + XOR-swizzled LDS ----------
__global__ __launch_bounds__(256) void k_out(const short* __restrict__ a16, const short* __restrict__ wo16,
                                             const float* __restrict__ bo, float* __restrict__ out){
  __shared__ short As[128*64];
  __shared__ short Bs[128*64];
  int tid = threadIdx.x, lane = tid&63, w = tid>>6;
  int m0 = blockIdx.x*128, n0 = blockIdx.y*128;
  int wrow = (w>>1)*64, wcol = (w&1)*64;
  int ln = lane&15, q = lane>>4;
  f4v acc[4][4];
  #pragma unroll
  for (int i = 0; i < 4; ++i)
    #pragma unroll
    for (int j = 0; j < 4; ++j) acc[i][j] = f4v{0.f,0.f,0.f,0.f};
  for (int it = 0; it < 32; ++it){
    int k0 = it*64;
    __syncthreads();
    #pragma unroll
    for (int t = 0; t < 4; ++t){   // 8 rows x 8 chunks per wave-load
      int r = w*32 + t*8 + (lane>>3);
      int c = lane&7;
      int gc8 = (c ^ (r&7))*8;
      gld16(a16  + (size_t)(m0+r)*2048 + k0 + gc8, &As[(w*32 + t*8)*64]);
      gld16(wo16 + (size_t)(n0+r)*2048 + k0 + gc8, &Bs[(w*32 + t*8)*64]);
    }
    __syncthreads();
    #pragma unroll
    for (int ks = 0; ks < 2; ++ks){
      s8v a[4], bb[4];
      int swz = ((ks*4 + q) ^ (ln&7))*8;
      #pragma unroll
      for (int i = 0; i < 4; ++i){
        a[i]  = *(const s8v*)&As[(wrow + i*16 + ln)*64 + swz];
        bb[i] = *(const s8v*)&Bs[(wcol + i*16 + ln)*64 + swz];
      }
      #pragma unroll
      for (int i = 0; i < 4; ++i)
        #pragma unroll
        for (int j = 0; j < 4; ++j) acc[i][j] = MFMA(a[i], bb[j], acc[i][j]);
    }
  }
  #pragma unroll
  for (int j = 0; j < 4; ++j){
    int col = n0 + wcol + j*16 + ln;
    float bv = bo[col];
    #pragma unroll
    for (int i = 0; i < 4; ++i)
      #pragma unroll
      for (int r = 0; r < 4; ++r){
        int row = m0 + wrow + i*16 + q*4 + r;
        out[(size_t)row*2048 + col] = acc[i][j][r] + bv;
      }
  }
}

extern "C" void kernel_launch(void* const* d_in, const int* in_sizes, int n_in,
                              void* d_out, int out_size, void* d_ws, size_t ws_size,
                              hipStream_t stream){
  const float* x  = (const float*)d_in[0];
  const float* Wq = (const float*)d_in[1];
  const float* bq = (const float*)d_in[2];
  const float* Wk = (const float*)d_in[3];
  const float* bk = (const float*)d_in[4];
  const float* Wv = (const float*)d_in[5];
  const float* bv = (const float*)d_in[6];
  const float* Wl = (const float*)d_in[7];
  const float* bl = (const float*)d_in[8];
  const float* Wo = (const float*)d_in[9];
  const float* bo = (const float*)d_in[10];
  float* out = (float*)d_out;

  char* p = (char*)d_ws;
  size_t off = 0;
  auto take = [&](size_t bytes)->char*{ char* r = p + off; off = (off + bytes + 255) & ~(size_t)255; return r; };
  short* x16   = (short*)take(16777216);  // (b,n,p,c) bf16; reused as attn-out after QKV consumed it
  short* q16   = (short*)take(16777216);
  short* k16   = (short*)take(16777216);
  short* v16   = (short*)take(16777216);
  short* vt16  = (short*)take(16777216);  // [b*16+h][c][n]
  short* wo16  = (short*)take(8388608);
  short* wq16  = (short*)take(32768);
  short* wk16  = (short*)take(32768);
  short* wv16  = (short*)take(32768);
  float* wcomb = (float*)take(4*129);
  float* logits= (float*)take(4*4096);
  float* maskp = (float*)take(4*4096);
  short* a16 = x16;   // alias: x16 dead after k_qkv3

  k_wcomb <<<1, 128, 0, stream>>>(Wq, bq, Wl, bl, wcomb);
  k_conv_w<<<16384, 256, 0, stream>>>(Wq, Wk, Wv, Wo, wq16, wk16, wv16, wo16);
  k_conv_x<<<4096, 256, 0, stream>>>(x, wcomb, x16, logits);
  k_mask  <<<4, 64, 0, stream>>>(logits, maskp);
  k_qkv3  <<<1024, 256, 0, stream>>>(x16, wq16, wk16, wv16, bq, bk, bv, q16, k16, v16);
  k_vtrans<<<dim3(64, 8), 256, 0, stream>>>(v16, vt16);
  k_attn  <<<dim3(8, 16, 4), 256, 0, stream>>>(q16, k16, vt16, maskp, a16);
  k_out   <<<dim3(32, 16), 256, 0, stream>>>(a16, wo16, bo, out);
}

// Round 4
// 262.118 us; speedup vs baseline: 1.3005x; 1.1401x over previous
//
#include <hip/hip_runtime.h>
#include <stdint.h>

// B=4, N=1024, C=128, P=16 positions, HEADS=16, DH=128, D=2048, MASK_NUM=25, SCALE=0.125
typedef __attribute__((ext_vector_type(8))) short s8v;   // 8 bf16 (A/B frag)
typedef __attribute__((ext_vector_type(4))) short s4v;
typedef __attribute__((ext_vector_type(4))) float f4v;   // C/D frag

#define MFMA(a,b,c) __builtin_amdgcn_mfma_f32_16x16x32_bf16((a),(b),(c),0,0,0)

__device__ __forceinline__ short f2bf(float f){   // RNE float->bf16 bits
  union { float f; unsigned u; } a; a.f = f;
  unsigned r = (a.u + 0x7fffu + ((a.u >> 16) & 1u)) >> 16;
  return (short)r;
}
__device__ __forceinline__ unsigned pk2(float a, float b){  // 2 bf16 packed in u32
  return (unsigned)(unsigned short)f2bf(a) | ((unsigned)(unsigned short)f2bf(b) << 16);
}

// async global->LDS DMA, 16B per lane; LDS dest = wave-uniform base + lane*16
__device__ __forceinline__ void gld16(const void* g, void* l){
  __builtin_amdgcn_global_load_lds((const __attribute__((address_space(1))) void*)g,
                                   (__attribute__((address_space(3))) void*)l, 16, 0, 0);
}

// ---------- weights fp32 -> bf16, + wcomb (block 0): wcomb[c]=sum Wl[o]Wq[o,c]; [128]=Wl.bq+bl ----------
__global__ void k_prep(const float* __restrict__ Wq, const float* __restrict__ Wk,
                       const float* __restrict__ Wv, const float* __restrict__ Wo,
                       const float* __restrict__ bq, const float* __restrict__ Wl,
                       const float* __restrict__ bl,
                       short* __restrict__ wq16, short* __restrict__ wk16,
                       short* __restrict__ wv16, short* __restrict__ wo16,
                       float* __restrict__ wcomb){
  int i = blockIdx.x*256 + threadIdx.x;      // grid 16384 -> exactly 4194304
  wo16[i] = f2bf(Wo[i]);
  if (i < 16384){ wq16[i] = f2bf(Wq[i]); wk16[i] = f2bf(Wk[i]); wv16[i] = f2bf(Wv[i]); }
  if (blockIdx.x == 0 && threadIdx.x < 128){
    int c = threadIdx.x;
    float s = 0.f;
    for (int o = 0; o < 128; ++o) s += Wl[o] * Wq[o*128 + c];
    wcomb[c] = s;
    if (c == 0){
      float t = 0.f; for (int o = 0; o < 128; ++o) t += Wl[o] * bq[o];
      wcomb[128] = t + bl[0];
    }
  }
}

// ---------- x fp32 -> bf16, plus fused logits (fp32) ----------
__global__ __launch_bounds__(256) void k_conv_x(const float* __restrict__ x, const float* __restrict__ wcomb,
                                                short* __restrict__ x16, float* __restrict__ logits){
  __shared__ float wc[128];
  __shared__ float part[4];
  int t = blockIdx.x, tid = threadIdx.x;     // one block per token
  if (tid < 128) wc[tid] = wcomb[tid];
  __syncthreads();
  const float* xp = x + (size_t)t*2048;
  short* op = x16 + (size_t)t*2048;
  float s = 0.f;
  #pragma unroll
  for (int j = 0; j < 2; ++j){
    int idx = j*1024 + tid*4;
    float4 v = *(const float4*)(xp + idx);
    s4v o; o.x = f2bf(v.x); o.y = f2bf(v.y); o.z = f2bf(v.z); o.w = f2bf(v.w);
    *(s4v*)(op + idx) = o;
    s += v.x*wc[idx&127] + v.y*wc[(idx+1)&127] + v.z*wc[(idx+2)&127] + v.w*wc[(idx+3)&127];
  }
  for (int off = 32; off; off >>= 1) s += __shfl_down(s, off);
  if ((tid&63) == 0) part[tid>>6] = s;
  __syncthreads();
  if (tid == 0) logits[t] = (part[0]+part[1]+part[2]+part[3])*(1.f/16.f) + wcomb[128];
}

// ---------- softmax + 25th-smallest threshold mask: one wave per batch ----------
__global__ __launch_bounds__(64) void k_mask(const float* __restrict__ logits, float* __restrict__ maskout){
  int b = blockIdx.x, lane = threadIdx.x;
  float v[16];
  #pragma unroll
  for (int i = 0; i < 16; ++i) v[i] = logits[b*1024 + i*64 + lane];
  float mx = v[0];
  #pragma unroll
  for (int i = 1; i < 16; ++i) mx = fmaxf(mx, v[i]);
  #pragma unroll
  for (int off = 32; off; off >>= 1) mx = fmaxf(mx, __shfl_xor(mx, off));
  float s = 0.f;
  #pragma unroll
  for (int i = 0; i < 16; ++i){ v[i] = __expf(v[i] - mx); s += v[i]; }
  #pragma unroll
  for (int off = 32; off; off >>= 1) s += __shfl_xor(s, off);
  float p[16];
  #pragma unroll
  for (int i = 0; i < 16; ++i){ p[i] = v[i] / s; v[i] = p[i]; }
  float thr = 0.f;
  for (int k = 0; k < 25; ++k){
    float lm = v[0]; int li = 0;
    #pragma unroll
    for (int i = 1; i < 16; ++i){ if (v[i] < lm){ lm = v[i]; li = i; } }
    float gm = lm;
    #pragma unroll
    for (int off = 32; off; off >>= 1) gm = fminf(gm, __shfl_xor(gm, off));
    if (k == 24) thr = gm;
    unsigned long long ball = __ballot(lm == gm);
    int owner = __ffsll((unsigned long long)ball) - 1;
    bool rm = (lane == owner);
    #pragma unroll
    for (int i = 0; i < 16; ++i){ if (rm && i == li) v[i] = 2.0f; }
  }
  #pragma unroll
  for (int i = 0; i < 16; ++i)
    maskout[b*1024 + i*64 + lane] = p[i] > thr ? 1.0f : p[i];
}

// ---------- merged QKV projection per (b, p, 64-token tile); Q pre-scaled 0.125*log2e;
//            mask folded into K and V; V written transposed to vt16 (k_vtrans fused) ----------
__global__ __launch_bounds__(256) void k_qkv3(const short* __restrict__ x16,
                                              const short* __restrict__ wq16, const short* __restrict__ wk16,
                                              const short* __restrict__ wv16,
                                              const float* __restrict__ bq, const float* __restrict__ bk,
                                              const float* __restrict__ bv, const float* __restrict__ maskp,
                                              short* __restrict__ q16, short* __restrict__ k16,
                                              short* __restrict__ vt16){
  __shared__ short At[64*136];    // also reused as the V-transpose buffer T
  __shared__ short Wt[128*136];
  int tid = threadIdx.x, lane = tid&63, w = tid>>6;
  int n0 = blockIdx.x*64, p = blockIdx.y, b = blockIdx.z;
  #pragma unroll
  for (int i = 0; i < 4; ++i){
    int ch = tid + 256*i; int r = ch>>4, c8 = (ch&15)*8;
    *(s8v*)&At[r*136 + c8] = *(const s8v*)(x16 + (size_t)(b*1024 + n0 + r)*2048 + p*128 + c8);
  }
  int ln = lane&15, q = lane>>4;
  float mvr[4];
  #pragma unroll
  for (int r = 0; r < 4; ++r) mvr[r] = maskp[b*1024 + n0 + w*16 + q*4 + r];
  const short* ws[3] = {wq16, wk16, wv16};
  const float* bs[3] = {bq, bk, bv};
  for (int ps = 0; ps < 3; ++ps){
    if (ps) __syncthreads();   // prior pass's reads of Wt done
    #pragma unroll
    for (int i = 0; i < 8; ++i){
      int ch = tid + 256*i; int r = ch>>4, c8 = (ch&15)*8;
      *(s8v*)&Wt[r*136 + c8] = *(const s8v*)(ws[ps] + r*128 + c8);
    }
    __syncthreads();
    f4v acc[8];
    #pragma unroll
    for (int cb = 0; cb < 8; ++cb) acc[cb] = f4v{0.f,0.f,0.f,0.f};
    #pragma unroll
    for (int ks = 0; ks < 4; ++ks){
      s8v a = *(const s8v*)&At[(w*16+ln)*136 + ks*32 + q*8];
      #pragma unroll
      for (int cb = 0; cb < 8; ++cb){
        s8v bb = *(const s8v*)&Wt[(cb*16+ln)*136 + ks*32 + q*8];
        acc[cb] = MFMA(a, bb, acc[cb]);
      }
    }
    const float* bp = bs[ps];
    if (ps < 2){
      float sc = (ps == 0) ? 0.180336881f : 1.0f;   // Q: 0.125*log2(e); K: 1 (mask per-row)
      short* op = (ps == 0) ? q16 : k16;
      #pragma unroll
      for (int cb = 0; cb < 8; ++cb){
        int col = cb*16 + ln;
        float bv2 = bp[col];
        #pragma unroll
        for (int r = 0; r < 4; ++r){
          int n = n0 + w*16 + q*4 + r;
          float mm = (ps == 1) ? mvr[r] : 1.0f;
          op[(size_t)(b*1024 + n)*2048 + p*128 + col] = f2bf((acc[cb][r] + bv2)*sc*mm);
        }
      }
    } else {
      __syncthreads();  // all At (a-frag) reads done before overwrite as T
      #pragma unroll
      for (int cb = 0; cb < 8; ++cb){
        int col = cb*16 + ln;
        float bv2 = bp[col];
        #pragma unroll
        for (int r = 0; r < 4; ++r)
          At[(w*16 + q*4 + r)*136 + col] = f2bf((acc[cb][r] + bv2)*mvr[r]);  // vf = (v+b)*mask
      }
      __syncthreads();
      #pragma unroll
      for (int i = 0; i < 4; ++i){
        int ch = tid + 256*i; int c = ch>>3, n8 = (ch&7)*8;
        s8v o;
        #pragma unroll
        for (int j = 0; j < 8; ++j) o[j] = At[(n8+j)*136 + c];
        *(s8v*)(vt16 + (size_t)((b*16+p)*128 + c)*1024 + n0 + n8) = o;
      }
    }
  }
}

// ---------- flash attention per (b,h): S^T via K·Q^T (lane-local row stats), denominator via
//            ones-column MFMA; mask pre-folded into k16/vt16; exp2-domain softmax ----------
__global__ __launch_bounds__(256, 2) void k_attn(const short* __restrict__ q16, const short* __restrict__ k16,
                                                 const short* __restrict__ vt16, short* __restrict__ a16){
  __shared__ short Ks[64*128];   // row j(64) x 16 chunks of 8; LDS chunk c holds global chunk c^(r&7)
  __shared__ short Vs[128*64];   // row c(128) x 8 chunks; same XOR
  __shared__ short Ps[128*72];   // raw pp, rows i-local(128, wave-private 32) x 64 j (stride 72)
  __shared__ float alS[128];     // per-row alpha broadcast (wave-private 32 each)
  int it = blockIdx.x, h = blockIdx.y, b = blockIdx.z;
  int i0 = it*128;
  int tid = threadIdx.x, lane = tid&63, w = tid>>6;
  int ln = lane&15, q = lane>>4;
  // Q fragments (2 groups of 16 rows x K=128) as B-operands, in registers
  s8v aq[2][4];
  const short* qbase = q16 + (size_t)(b*1024 + i0 + w*32)*2048 + h*128;
  #pragma unroll
  for (int g = 0; g < 2; ++g)
    #pragma unroll
    for (int ks = 0; ks < 4; ++ks)
      aq[g][ks] = *(const s8v*)(qbase + (size_t)(g*16+ln)*2048 + ks*32 + q*8);
  s8v ones;
  #pragma unroll
  for (int j = 0; j < 8; ++j) ones[j] = (short)0x3F80;   // bf16 1.0
  f4v o[2][8], o9[2];
  #pragma unroll
  for (int g = 0; g < 2; ++g){
    #pragma unroll
    for (int cb = 0; cb < 8; ++cb) o[g][cb] = f4v{0.f,0.f,0.f,0.f};
    o9[g] = f4v{0.f,0.f,0.f,0.f};
  }
  float mo[2] = {-3.0e38f, -3.0e38f};
  const short* kbase = k16 + (size_t)(b*1024)*2048 + h*128;
  const short* vbase = vt16 + (size_t)((b*16+h)*128)*1024;
  for (int jt = 0; jt < 16; ++jt){
    int j0 = jt*64;
    __syncthreads();   // all waves done reading Ks/Vs of previous tile before DMA overwrite
    #pragma unroll
    for (int t = 0; t < 4; ++t){   // K: 4 rows x 16 chunks per wave-load
      int r = w*16 + t*4 + (lane>>4);
      int c = lane&15;
      gld16(kbase + (size_t)(j0 + r)*2048 + ((c ^ (r&7))*8), &Ks[(w*16 + t*4)*128]);
    }
    #pragma unroll
    for (int t = 0; t < 4; ++t){   // V: 8 rows x 8 chunks per wave-load
      int r = w*32 + t*8 + (lane>>3);
      int c = lane&7;
      gld16(vbase + (size_t)r*1024 + j0 + ((c ^ (r&7))*8), &Vs[(w*32 + t*8)*64]);
    }
    __syncthreads();   // DMA complete
    // S^T: rows j (mb*16 + q*4 + r), cols i (= ln, per group g)
    f4v st[2][4];
    #pragma unroll
    for (int g = 0; g < 2; ++g)
      #pragma unroll
      for (int mb = 0; mb < 4; ++mb) st[g][mb] = f4v{0.f,0.f,0.f,0.f};
    #pragma unroll
    for (int ks = 0; ks < 4; ++ks)
      #pragma unroll
      for (int mb = 0; mb < 4; ++mb){
        s8v ka = *(const s8v*)&Ks[(mb*16+ln)*128 + (((ks*4 + q) ^ (ln&7))*8)];
        st[0][mb] = MFMA(ka, aq[0][ks], st[0][mb]);
        st[1][mb] = MFMA(ka, aq[1][ks], st[1][mb]);
      }
    // softmax: each lane owns ONE Q-row per group (i = g*16+ln); j-coverage split over q-quads
    #pragma unroll
    for (int g = 0; g < 2; ++g){
      float mx = st[g][0][0];
      #pragma unroll
      for (int mb = 0; mb < 4; ++mb)
        #pragma unroll
        for (int r = 0; r < 4; ++r) mx = fmaxf(mx, st[g][mb][r]);
      mx = fmaxf(mx, __shfl_xor(mx, 16));
      mx = fmaxf(mx, __shfl_xor(mx, 32));
      float mnew = fmaxf(mo[g], mx);
      float al = exp2f(mo[g] - mnew);
      mo[g] = mnew;
      int prow = (w*32 + g*16 + ln)*72;
      #pragma unroll
      for (int mb = 0; mb < 4; ++mb){
        uint2 u;
        u.x = pk2(exp2f(st[g][mb][0] - mnew), exp2f(st[g][mb][1] - mnew));
        u.y = pk2(exp2f(st[g][mb][2] - mnew), exp2f(st[g][mb][3] - mnew));
        *(uint2*)&Ps[prow + mb*16 + q*4] = u;
      }
      if (q == 0) alS[w*32 + g*16 + ln] = al;
    }
    // rescale O (and denominator o9) by per-row alpha, broadcast via wave-private LDS
    float alr[2][4];
    #pragma unroll
    for (int g = 0; g < 2; ++g)
      #pragma unroll
      for (int r = 0; r < 4; ++r) alr[g][r] = alS[w*32 + g*16 + q*4 + r];
    #pragma unroll
    for (int g = 0; g < 2; ++g){
      #pragma unroll
      for (int cb = 0; cb < 8; ++cb)
        #pragma unroll
        for (int r = 0; r < 4; ++r) o[g][cb][r] *= alr[g][r];
      #pragma unroll
      for (int r = 0; r < 4; ++r) o9[g][r] *= alr[g][r];
    }
    // PV: O[i][c] += P[i][j] V^T[c][j]; ones-column accumulates the denominator
    #pragma unroll
    for (int ks = 0; ks < 2; ++ks){
      s8v pa[2];
      #pragma unroll
      for (int g = 0; g < 2; ++g) pa[g] = *(const s8v*)&Ps[(w*32 + g*16 + ln)*72 + ks*32 + q*8];
      #pragma unroll
      for (int cb = 0; cb < 8; ++cb){
        s8v bb = *(const s8v*)&Vs[(cb*16+ln)*64 + (((ks*4 + q) ^ (ln&7))*8)];
        o[0][cb] = MFMA(pa[0], bb, o[0][cb]);
        o[1][cb] = MFMA(pa[1], bb, o[1][cb]);
      }
      o9[0] = MFMA(pa[0], ones, o9[0]);
      o9[1] = MFMA(pa[1], ones, o9[1]);
    }
  }
  #pragma unroll
  for (int g = 0; g < 2; ++g)
    #pragma unroll
    for (int cb = 0; cb < 8; ++cb){
      int col = cb*16 + ln;
      #pragma unroll
      for (int r = 0; r < 4; ++r){
        int row = i0 + w*32 + g*16 + q*4 + r;
        a16[(size_t)(b*1024 + row)*2048 + h*128 + col] = f2bf(o[g][cb][r] / o9[g][r]);
      }
    }
}

// ---------- output projection: out(4096,2048) = A16 . Wo^T + bo, global_load_lds + XOR-swizzled LDS ----------
__global__ __launch_bounds__(256) void k_out(const short* __restrict__ a16, const short* __restrict__ wo16,
                                             const float* __restrict__ bo, float* __restrict__ out){
  __shared__ short As[128*64];
  __shared__ short Bs[128*64];
  int tid = threadIdx.x, lane = tid&63, w = tid>>6;
  int m0 = blockIdx.x*128, n0 = blockIdx.y*128;
  int wrow = (w>>1)*64, wcol = (w&1)*64;
  int ln = lane&15, q = lane>>4;
  f4v acc[4][4];
  #pragma unroll
  for (int i = 0; i < 4; ++i)
    #pragma unroll
    for (int j = 0; j < 4; ++j) acc[i][j] = f4v{0.f,0.f,0.f,0.f};
  for (int it = 0; it < 32; ++it){
    int k0 = it*64;
    __syncthreads();
    #pragma unroll
    for (int t = 0; t < 4; ++t){   // 8 rows x 8 chunks per wave-load
      int r = w*32 + t*8 + (lane>>3);
      int c = lane&7;
      int gc8 = (c ^ (r&7))*8;
      gld16(a16  + (size_t)(m0+r)*2048 + k0 + gc8, &As[(w*32 + t*8)*64]);
      gld16(wo16 + (size_t)(n0+r)*2048 + k0 + gc8, &Bs[(w*32 + t*8)*64]);
    }
    __syncthreads();
    #pragma unroll
    for (int ks = 0; ks < 2; ++ks){
      s8v a[4], bb[4];
      int swz = ((ks*4 + q) ^ (ln&7))*8;
      #pragma unroll
      for (int i = 0; i < 4; ++i){
        a[i]  = *(const s8v*)&As[(wrow + i*16 + ln)*64 + swz];
        bb[i] = *(const s8v*)&Bs[(wcol + i*16 + ln)*64 + swz];
      }
      #pragma unroll
      for (int i = 0; i < 4; ++i)
        #pragma unroll
        for (int j = 0; j < 4; ++j) acc[i][j] = MFMA(a[i], bb[j], acc[i][j]);
    }
  }
  #pragma unroll
  for (int j = 0; j < 4; ++j){
    int col = n0 + wcol + j*16 + ln;
    float bv = bo[col];
    #pragma unroll
    for (int i = 0; i < 4; ++i)
      #pragma unroll
      for (int r = 0; r < 4; ++r){
        int row = m0 + wrow + i*16 + q*4 + r;
        out[(size_t)row*2048 + col] = acc[i][j][r] + bv;
      }
  }
}

extern "C" void kernel_launch(void* const* d_in, const int* in_sizes, int n_in,
                              void* d_out, int out_size, void* d_ws, size_t ws_size,
                              hipStream_t stream){
  const float* x  = (const float*)d_in[0];
  const float* Wq = (const float*)d_in[1];
  const float* bq = (const float*)d_in[2];
  const float* Wk = (const float*)d_in[3];
  const float* bk = (const float*)d_in[4];
  const float* Wv = (const float*)d_in[5];
  const float* bv = (const float*)d_in[6];
  const float* Wl = (const float*)d_in[7];
  const float* bl = (const float*)d_in[8];
  const float* Wo = (const float*)d_in[9];
  const float* bo = (const float*)d_in[10];
  float* out = (float*)d_out;

  char* p = (char*)d_ws;
  size_t off = 0;
  auto take = [&](size_t bytes)->char*{ char* r = p + off; off = (off + bytes + 255) & ~(size_t)255; return r; };
  short* x16   = (short*)take(16777216);  // (b,n,p,c) bf16; reused as attn-out after k_qkv3
  short* q16   = (short*)take(16777216);
  short* k16   = (short*)take(16777216);  // pre-masked kf
  short* vt16  = (short*)take(16777216);  // [b*16+h][c][n], pre-masked vf, transposed
  short* wo16  = (short*)take(8388608);
  short* wq16  = (short*)take(32768);
  short* wk16  = (short*)take(32768);
  short* wv16  = (short*)take(32768);
  float* wcomb = (float*)take(4*129);
  float* logits= (float*)take(4*4096);
  float* maskp = (float*)take(4*4096);
  short* a16 = x16;   // alias: x16 dead after k_qkv3

  k_prep  <<<16384, 256, 0, stream>>>(Wq, Wk, Wv, Wo, bq, Wl, bl, wq16, wk16, wv16, wo16, wcomb);
  k_conv_x<<<4096, 256, 0, stream>>>(x, wcomb, x16, logits);
  k_mask  <<<4, 64, 0, stream>>>(logits, maskp);
  k_qkv3  <<<dim3(16, 16, 4), 256, 0, stream>>>(x16, wq16, wk16, wv16, bq, bk, bv, maskp, q16, k16, vt16);
  k_attn  <<<dim3(8, 16, 4), 256, 0, stream>>>(q16, k16, vt16, a16);
  k_out   <<<dim3(32, 16), 256, 0, stream>>>(a16, wo16, bo, out);
}